// Round 7
// baseline (293.036 us; speedup 1.0000x reference)
//
#include <hip/hip_runtime.h>

typedef unsigned short u16;
typedef unsigned char u8;
typedef float f32x4 __attribute__((ext_vector_type(4)));

#define P_OUT 29791      // 31^3
#define PPAD  29824      // 233*128
#define NBAT  4
#define NCH   512
#define KDIM  128

// ---- pack 4 fp32 -> 4 fp8 e4m3 (RNE, OCP) ----
__device__ __forceinline__ unsigned pk4_fp8(float a, float b, float c, float d) {
  int v = __builtin_amdgcn_cvt_pk_fp8_f32(a, b, 0, false);   // low word
  v = __builtin_amdgcn_cvt_pk_fp8_f32(c, d, v, true);        // high word
  return (unsigned)v;
}

// ---- fused prep ----
// blocks [0, 3844): y-prep, one block per (nb, d, h): stage x slab
//   [16c][2dd][2hh][32w] (8 KB) in LDS coalesced, pack 31 fp8 rows + ysq.
// blocks [3844, 3876): w-prep (512 rows, 16 rows/block).
__global__ void prep_kernel(const float* __restrict__ x,
                            const float* __restrict__ w,
                            u8* __restrict__ yb, float* __restrict__ ysq,
                            u8* __restrict__ wb, float* __restrict__ wsq) {
  const int tid = threadIdx.x;
  const int b = blockIdx.x;
  if (b >= 3844) {   // ---- w-prep ----
    const int g = (b - 3844) * 16 + (tid >> 4);  // 0..511
    const int c = tid & 15;
    const float4* wr = (const float4*)(w + g * 128 + c * 8);
    float4 f0 = wr[0], f1 = wr[1];
    float s = f0.x*f0.x + f0.y*f0.y + f0.z*f0.z + f0.w*f0.w
            + f1.x*f1.x + f1.y*f1.y + f1.z*f1.z + f1.w*f1.w;
#pragma unroll
    for (int m = 1; m < 16; m <<= 1) s += __shfl_xor(s, m, 64);
    uint2 pk;
    pk.x = pk4_fp8(f0.x, f0.y, f0.z, f0.w);
    pk.y = pk4_fp8(f1.x, f1.y, f1.z, f1.w);
    *(uint2*)(wb + g * 128 + c * 8) = pk;
    if (c == 0) wsq[g] = s;
    return;
  }
  // ---- y-prep ----
  __shared__ float xs[16][4][33];   // [c][r=kd*2+kh][w], +1 pad -> 2-way max
  const int nb = b / 961;
  const int rem = b - nb * 961;
  const int d = rem / 31;
  const int h = rem - d * 31;
  const float* xb = x + ((size_t)nb << 19) + d * 1024 + h * 32;
  // load 2048 floats, fully coalesced (contiguous 128 B per (c,r))
#pragma unroll
  for (int t = 0; t < 8; ++t) {
    const int e = tid + 256 * t;
    const int c = e >> 7;
    const int r = (e >> 5) & 3;
    const int wv = e & 31;
    xs[c][r][wv] = xb[((size_t)c << 15) + (r >> 1) * 1024 + (r & 1) * 32 + wv];
  }
  __syncthreads();
  const int cs = tid & 15;    // channel = k-chunk of 8
  const int wv0 = tid >> 4;
#pragma unroll
  for (int round = 0; round < 2; ++round) {
    const int wv = wv0 + 16 * round;
    if (wv <= 30) {           // uniform per 16-lane group
      const float v0 = xs[cs][0][wv], v1 = xs[cs][0][wv + 1];
      const float v2 = xs[cs][1][wv], v3 = xs[cs][1][wv + 1];
      const float v4 = xs[cs][2][wv], v5 = xs[cs][2][wv + 1];
      const float v6 = xs[cs][3][wv], v7 = xs[cs][3][wv + 1];
      float s = v0*v0 + v1*v1 + v2*v2 + v3*v3 + v4*v4 + v5*v5 + v6*v6 + v7*v7;
#pragma unroll
      for (int m = 1; m < 16; m <<= 1) s += __shfl_xor(s, m, 64);
      const int g = nb * PPAD + d * 961 + h * 31 + wv;
      uint2 pk;
      pk.x = pk4_fp8(v0, v1, v2, v3);
      pk.y = pk4_fp8(v4, v5, v6, v7);
      *(uint2*)(yb + (size_t)g * 128 + cs * 8) = pk;
      if (cs == 0) ysq[g] = s;
    }
  }
}

// async global->LDS, 16 B per lane, lands at ldsbase + lane*16
#define GLDS(g, l) __builtin_amdgcn_global_load_lds(                         \
    (const __attribute__((address_space(1))) unsigned int*)(g),              \
    (__attribute__((address_space(3))) unsigned int*)(l), 16, 0, 0)

// ---- GEMM + epilogue: out[n][ch][p] = exp(-(ysq[p] - 2*y.w + wsq[ch])) ----
// fp8 e4m3. Block = 256 ch x 128 p: ONE staging phase (two 16 KB w-tiles +
// one 16 KB y-tile = 48 KB LDS), ONE barrier, then two ct-passes of
// 4x mfma_f32_16x16x32_fp8_fp8 k-steps + epilogue each. No mid-kernel
// barrier (LDS never rewritten): pass-0 stores overlap pass-1 MFMAs.
// A = w (m=ch), B = y (n=p); C/D col(lane&15)=p contiguous -> 64 B segments.
// LDS: [row][8 chunks of 16 B], chunk pos = chunk ^ (row&7): lane-linear
// staging; b64 frag reads land uniform 4 dwords/bank (512 B/instr minimum).
__global__ void gauss_gemm_kernel(const u8* __restrict__ yb,
                                  const float* __restrict__ ysq,
                                  const u8* __restrict__ wb,
                                  const float* __restrict__ wsq,
                                  float* __restrict__ out) {
  __shared__ __align__(16) u8 Ws[256 * 128];  // two w tiles [ch][k], 32 KB
  __shared__ __align__(16) u8 Ys[128 * 128];  // y tile     [p][k],  16 KB

  const int bid = blockIdx.x;
  const int ct2 = bid & 1;           // 2 super ch-tiles of 256
  const int pt = (bid >> 1) % 233;   // 233 p tiles
  const int nb = bid / 466;          // 4 batches
  const int p0 = pt * 128;
  const int cb = ct2 * 256;

  const int tid = threadIdx.x;
  const int wid = tid >> 6;
  const int lane = tid & 63;
  const int quad = lane >> 4;
  const int col = lane & 15;
  const int wch = wid & 1;   // wave ch-half
  const int wp = wid >> 1;   // wave p-half

  const size_t ybase = ((size_t)nb * PPAD + p0) * 128;   // bytes

  // ---- stage W (2048 chunks of 16 B) + Y (1024 chunks) ----
#pragma unroll
  for (int t = 0; t < 8; ++t) {
    const int Lb = wid * 512 + t * 64;      // wave-uniform chunk base
    const int L = Lb + lane;
    const int row = L >> 3;                 // 0..255
    const int jc = (L & 7) ^ (row & 7);     // unswizzled 16 B k-chunk
    GLDS(wb + (size_t)(cb + row) * 128 + jc * 16, &Ws[Lb * 16]);
  }
#pragma unroll
  for (int t = 0; t < 4; ++t) {
    const int Lb = wid * 256 + t * 64;
    const int L = Lb + lane;
    const int row = L >> 3;                 // 0..127
    const int jc = (L & 7) ^ (row & 7);
    GLDS(yb + ybase + (size_t)row * 128 + jc * 16, &Ys[Lb * 16]);
  }

  // epilogue p indices / ysq (pass-independent)
  float ysv[4];
  int pj[4];
#pragma unroll
  for (int j = 0; j < 4; ++j) {
    pj[j] = p0 + wp * 64 + j * 16 + col;
    ysv[j] = ysq[(size_t)nb * PPAD + pj[j]];
  }

  __syncthreads();   // drains GLDS (vmcnt) + all lanes ready

  const int c16b = quad >> 1;   // lane's 16 B-chunk offset within ks window
  const int hoff = (quad & 1) * 8;

#pragma unroll
  for (int cth = 0; cth < 2; ++cth) {
    const int c0 = cb + cth * 128;
    const u8* Wt = &Ws[cth * 128 * 128];

    f32x4 acc[4][4];
#pragma unroll
    for (int i = 0; i < 4; ++i)
#pragma unroll
      for (int j = 0; j < 4; ++j) acc[i][j] = (f32x4){0.f, 0.f, 0.f, 0.f};

#pragma unroll
    for (int ks = 0; ks < 4; ++ks) {
      long long a[4], b[4];
#pragma unroll
      for (int i = 0; i < 4; ++i) {
        const int rowA = wch * 64 + i * 16 + col;
        const int pa = (ks * 2 + c16b) ^ (rowA & 7);
        a[i] = *(const long long*)&Wt[rowA * 128 + pa * 16 + hoff];
        const int rowB = wp * 64 + i * 16 + col;
        const int pb = (ks * 2 + c16b) ^ (rowB & 7);
        b[i] = *(const long long*)&Ys[rowB * 128 + pb * 16 + hoff];
      }
#pragma unroll
      for (int i = 0; i < 4; ++i)
#pragma unroll
        for (int j = 0; j < 4; ++j)
          acc[i][j] = __builtin_amdgcn_mfma_f32_16x16x32_fp8_fp8(a[i], b[j],
                                                                 acc[i][j], 0, 0, 0);
    }

    // epilogue: dist = ysq - 2*cross + wsq ; out = exp(-dist). fire-and-forget
#pragma unroll
    for (int i = 0; i < 4; ++i) {
#pragma unroll
      for (int r = 0; r < 4; ++r) {
        const int ch = c0 + wch * 64 + i * 16 + quad * 4 + r;
        const float wsv = wsq[ch];
        float* ob = out + ((size_t)(nb * NCH + ch)) * P_OUT;
#pragma unroll
        for (int j = 0; j < 4; ++j) {
          if (pj[j] < P_OUT) {
            const float dist = ysv[j] - 2.f * acc[i][j][r] + wsv;
            ob[pj[j]] = __expf(-dist);
          }
        }
      }
    }
  }
}

extern "C" void kernel_launch(void* const* d_in, const int* in_sizes, int n_in,
                              void* d_out, int out_size, void* d_ws, size_t ws_size,
                              hipStream_t stream) {
  const float* x = (const float*)d_in[0];
  const float* w = (const float*)d_in[1];
  float* out = (float*)d_out;
  char* ws = (char*)d_ws;
  // workspace layout (128B-aligned):
  u8* yb     = (u8*)ws;                      // 4*29824*128 fp8 = 15,269,888 B
  float* ysq = (float*)(ws + 15269888);      // 119,296 * 4     =    477,184 B
  u8* wb     = (u8*)(ws + 15747072);         // 512*128 fp8     =     65,536 B
  float* wsq = (float*)(ws + 15812608);      // 512*4           =      2,048 B

  prep_kernel<<<3876, 256, 0, stream>>>(x, w, yb, ysq, wb, wsq);
  gauss_gemm_kernel<<<1864, 256, 0, stream>>>(yb, ysq, wb, wsq, out);
}

// Round 8
// 278.595 us; speedup vs baseline: 1.0518x; 1.0518x over previous
//
#include <hip/hip_runtime.h>

typedef unsigned short u16;
typedef unsigned char u8;
typedef float f32x4 __attribute__((ext_vector_type(4)));

#define P_OUT 29791      // 31^3
#define PPAD  29824      // 233*128
#define NBAT  4
#define NCH   512
#define KDIM  128

// ---- pack 4 fp32 -> 4 fp8 e4m3 (RNE, OCP) ----
__device__ __forceinline__ unsigned pk4_fp8(float a, float b, float c, float d) {
  int v = __builtin_amdgcn_cvt_pk_fp8_f32(a, b, 0, false);   // low word
  v = __builtin_amdgcn_cvt_pk_fp8_f32(c, d, v, true);        // high word
  return (unsigned)v;
}

// ---- fused prep ----
// blocks [0, 3844): y-prep, one block per (nb, d, h): stage x slab
//   [16c][2dd][2hh][32w] (8 KB) in LDS coalesced, pack 31 fp8 rows + ysq.
// blocks [3844, 3876): w-prep (512 rows, 16 rows/block).
__global__ void prep_kernel(const float* __restrict__ x,
                            const float* __restrict__ w,
                            u8* __restrict__ yb, float* __restrict__ ysq,
                            u8* __restrict__ wb, float* __restrict__ wsq) {
  const int tid = threadIdx.x;
  const int b = blockIdx.x;
  if (b >= 3844) {   // ---- w-prep ----
    const int g = (b - 3844) * 16 + (tid >> 4);  // 0..511
    const int c = tid & 15;
    const float4* wr = (const float4*)(w + g * 128 + c * 8);
    float4 f0 = wr[0], f1 = wr[1];
    float s = f0.x*f0.x + f0.y*f0.y + f0.z*f0.z + f0.w*f0.w
            + f1.x*f1.x + f1.y*f1.y + f1.z*f1.z + f1.w*f1.w;
#pragma unroll
    for (int m = 1; m < 16; m <<= 1) s += __shfl_xor(s, m, 64);
    uint2 pk;
    pk.x = pk4_fp8(f0.x, f0.y, f0.z, f0.w);
    pk.y = pk4_fp8(f1.x, f1.y, f1.z, f1.w);
    *(uint2*)(wb + g * 128 + c * 8) = pk;
    if (c == 0) wsq[g] = s;
    return;
  }
  // ---- y-prep ----
  __shared__ float xs[16][4][33];   // [c][r=kd*2+kh][w], +1 pad -> 2-way max
  const int nb = b / 961;
  const int rem = b - nb * 961;
  const int d = rem / 31;
  const int h = rem - d * 31;
  const float* xb = x + ((size_t)nb << 19) + d * 1024 + h * 32;
  // load 2048 floats, fully coalesced (contiguous 128 B per (c,r))
#pragma unroll
  for (int t = 0; t < 8; ++t) {
    const int e = tid + 256 * t;
    const int c = e >> 7;
    const int r = (e >> 5) & 3;
    const int wv = e & 31;
    xs[c][r][wv] = xb[((size_t)c << 15) + (r >> 1) * 1024 + (r & 1) * 32 + wv];
  }
  __syncthreads();
  const int cs = tid & 15;    // channel = k-chunk of 8
  const int wv0 = tid >> 4;
#pragma unroll
  for (int round = 0; round < 2; ++round) {
    const int wv = wv0 + 16 * round;
    if (wv <= 30) {           // uniform per 16-lane group
      const float v0 = xs[cs][0][wv], v1 = xs[cs][0][wv + 1];
      const float v2 = xs[cs][1][wv], v3 = xs[cs][1][wv + 1];
      const float v4 = xs[cs][2][wv], v5 = xs[cs][2][wv + 1];
      const float v6 = xs[cs][3][wv], v7 = xs[cs][3][wv + 1];
      float s = v0*v0 + v1*v1 + v2*v2 + v3*v3 + v4*v4 + v5*v5 + v6*v6 + v7*v7;
#pragma unroll
      for (int m = 1; m < 16; m <<= 1) s += __shfl_xor(s, m, 64);
      const int g = nb * PPAD + d * 961 + h * 31 + wv;
      uint2 pk;
      pk.x = pk4_fp8(v0, v1, v2, v3);
      pk.y = pk4_fp8(v4, v5, v6, v7);
      *(uint2*)(yb + (size_t)g * 128 + cs * 8) = pk;
      if (cs == 0) ysq[g] = s;
    }
  }
}

// async global->LDS, 16 B per lane, lands at ldsbase + lane*16
#define GLDS(g, l) __builtin_amdgcn_global_load_lds(                         \
    (const __attribute__((address_space(1))) unsigned int*)(g),              \
    (__attribute__((address_space(3))) unsigned int*)(l), 16, 0, 0)

// ---- GEMM + epilogue: out[n][ch][p] = exp(-(ysq[p] - 2*y.w + wsq[ch])) ----
// fp8 e4m3 operands: full K=128 staged in ONE 32 KB LDS stage (16 KB w-tile
// + 16 KB y-tile), single barrier, 4 ks-steps of mfma_f32_16x16x32_fp8_fp8.
// Roles as in the verified bf16 version: A = w (m=ch), B = y (n=p); C/D is
// dtype-independent -> col(lane&15)=p contiguous, 64 B store segments.
// LDS: [row][8 chunks of 16 B], chunk pos = chunk ^ (row&7): lane-linear
// staging; b64 frag reads land uniform 4 dwords/bank (= 512 B/instr min).
__global__ void gauss_gemm_kernel(const u8* __restrict__ yb,
                                  const float* __restrict__ ysq,
                                  const u8* __restrict__ wb,
                                  const float* __restrict__ wsq,
                                  float* __restrict__ out) {
  __shared__ __align__(16) u8 Ws[128 * 128];  // w tile [ch][k], 16 KB
  __shared__ __align__(16) u8 Ys[128 * 128];  // y tile [p][k],  16 KB

  const int bid = blockIdx.x;
  const int ct = bid & 3;            // 4 ch tiles
  const int pt = (bid >> 2) % 233;   // 233 p tiles
  const int nb = bid / 932;          // 4 batches
  const int p0 = pt * 128;
  const int c0 = ct * 128;

  const int tid = threadIdx.x;
  const int wid = tid >> 6;
  const int lane = tid & 63;
  const int quad = lane >> 4;
  const int col = lane & 15;
  const int wch = wid & 1;   // wave ch-half
  const int wp = wid >> 1;   // wave p-half

  const size_t ybase = ((size_t)nb * PPAD + p0) * 128;   // bytes

  // ---- stage full K: 1024 chunks of 16 B per tile, 4 rounds each ----
#pragma unroll
  for (int t = 0; t < 4; ++t) {
    const int Lb = (wid * 4 + t) * 64;      // chunk base (wave-uniform)
    const int L = Lb + lane;
    const int row = L >> 3;                 // 8 chunks per 128 B row
    const int jc = (L & 7) ^ (row & 7);     // unswizzled 16B k-chunk
    GLDS(wb + (size_t)(c0 + row) * 128 + jc * 16, &Ws[Lb * 16]);
    GLDS(yb + ybase + (size_t)row * 128 + jc * 16, &Ys[Lb * 16]);
  }

  f32x4 acc[4][4];
#pragma unroll
  for (int i = 0; i < 4; ++i)
#pragma unroll
    for (int j = 0; j < 4; ++j) acc[i][j] = (f32x4){0.f, 0.f, 0.f, 0.f};

  __syncthreads();   // drains GLDS (vmcnt) + all lanes ready

  const int c16b = quad >> 1;   // lane's 16B-chunk offset within ks window
  const int hoff = (quad & 1) * 8;
#pragma unroll
  for (int ks = 0; ks < 4; ++ks) {
    long long a[4], b[4];
#pragma unroll
    for (int i = 0; i < 4; ++i) {
      const int rowA = wch * 64 + i * 16 + col;
      const int pa = (ks * 2 + c16b) ^ (rowA & 7);
      a[i] = *(const long long*)&Ws[rowA * 128 + pa * 16 + hoff];
      const int rowB = wp * 64 + i * 16 + col;
      const int pb = (ks * 2 + c16b) ^ (rowB & 7);
      b[i] = *(const long long*)&Ys[rowB * 128 + pb * 16 + hoff];
    }
#pragma unroll
    for (int i = 0; i < 4; ++i)
#pragma unroll
      for (int j = 0; j < 4; ++j)
        acc[i][j] = __builtin_amdgcn_mfma_f32_16x16x32_fp8_fp8(a[i], b[j],
                                                               acc[i][j], 0, 0, 0);
  }
  // no trailing barrier: stores below are fire-and-forget to kernel end

  // epilogue: dist = ysq - 2*cross + wsq ; out = exp(-dist)
  float ysv[4];
  int pj[4];
#pragma unroll
  for (int j = 0; j < 4; ++j) {
    pj[j] = p0 + wp * 64 + j * 16 + col;
    ysv[j] = ysq[(size_t)nb * PPAD + pj[j]];
  }
#pragma unroll
  for (int i = 0; i < 4; ++i) {
#pragma unroll
    for (int r = 0; r < 4; ++r) {
      const int ch = c0 + wch * 64 + i * 16 + quad * 4 + r;
      const float wsv = wsq[ch];
      float* ob = out + ((size_t)(nb * NCH + ch)) * P_OUT;
#pragma unroll
      for (int j = 0; j < 4; ++j) {
        if (pj[j] < P_OUT) {
          const float dist = ysv[j] - 2.f * acc[i][j][r] + wsv;
          ob[pj[j]] = __expf(-dist);
        }
      }
    }
  }
}

extern "C" void kernel_launch(void* const* d_in, const int* in_sizes, int n_in,
                              void* d_out, int out_size, void* d_ws, size_t ws_size,
                              hipStream_t stream) {
  const float* x = (const float*)d_in[0];
  const float* w = (const float*)d_in[1];
  float* out = (float*)d_out;
  char* ws = (char*)d_ws;
  // workspace layout (128B-aligned):
  u8* yb     = (u8*)ws;                      // 4*29824*128 fp8 = 15,269,888 B
  float* ysq = (float*)(ws + 15269888);      // 119,296 * 4     =    477,184 B
  u8* wb     = (u8*)(ws + 15747072);         // 512*128 fp8     =     65,536 B
  float* wsq = (float*)(ws + 15812608);      // 512*4           =      2,048 B

  prep_kernel<<<3876, 256, 0, stream>>>(x, w, yb, ysq, wb, wsq);
  gauss_gemm_kernel<<<3728, 256, 0, stream>>>(yb, ysq, wb, wsq, out);
}